// Round 8
// baseline (1230.626 us; speedup 1.0000x reference)
//
#include <hip/hip_runtime.h>
#include <hip/hip_fp16.h>
#include <stdint.h>

#define B_ROWS 65536
#define K_DIM 3072
#define N_DIM 1024

#define BM 256
#define BN 256
#define BK 64
#define NBLK 4            // N_DIM / BN
#define THREADS 512
#define KSTEPS (K_DIM / BK)   // 48
#define MARGIN 6.0e-3f
#define FB_CAP 8192
#define NWG ((B_ROWS / BM) * NBLK)   // 1024

typedef _Float16 f16x8 __attribute__((ext_vector_type(8)));
typedef float f32x4 __attribute__((ext_vector_type(4)));

#define BARR() __builtin_amdgcn_s_barrier()
#define VMCNT12() asm volatile("s_waitcnt vmcnt(12)" ::: "memory")
#define LGKM0() asm volatile("s_waitcnt lgkmcnt(0)" ::: "memory")
#define SCHEDB() __builtin_amdgcn_sched_barrier(0)

__device__ __forceinline__ float gelu_exact(float v) {
  return 0.5f * v * (1.0f + erff(v * 0.7071067811865476f));
}

__device__ __forceinline__ void gld16(const void* g, void* l) {
  __builtin_amdgcn_global_load_lds(
      (const __attribute__((address_space(1))) void*)g,
      (__attribute__((address_space(3))) void*)l, 16, 0, 0);
}

__device__ __forceinline__ f16x8 cvt8(const float4 a, const float4 b) {
  f16x8 h;
  h[0] = (_Float16)a.x; h[1] = (_Float16)a.y; h[2] = (_Float16)a.z; h[3] = (_Float16)a.w;
  h[4] = (_Float16)b.x; h[5] = (_Float16)b.y; h[6] = (_Float16)b.z; h[7] = (_Float16)b.w;
  return h;
}

// ---- kernel 1: build swizzled fp16 B-image of w1 (+ zero fb_cnt) ------------
// Image per (nb, kt): 256 rows (n) x 64 cols (k) fp16, 32KB, laid out exactly
// as the LDS tile: element (row, su*8+j) = w1[kt*64 + (su^(row&7))*8 + j][nb*256+row]
__global__ void k_w1t(const float* __restrict__ w1, _Float16* __restrict__ w1img,
                      int* __restrict__ fb_cnt) {
  if (blockIdx.x == 0 && blockIdx.y == 0 && threadIdx.x == 0) *fb_cnt = 0;
  __shared__ _Float16 lw[64][264];
  const int kt = blockIdx.x, nb = blockIdx.y;
  const int t = threadIdx.x;
  for (int r = 0; r < 64; ++r)
    lw[r][t] = (_Float16)w1[(size_t)(kt * 64 + r) * N_DIM + nb * 256 + t];
  __syncthreads();
  const size_t tbase = ((size_t)(nb * KSTEPS + kt)) << 14;
#pragma unroll
  for (int i = 0; i < 8; ++i) {
    const int U = i * 256 + t;
    const int row = U >> 3, su = U & 7;
    const int u = su ^ (row & 7);
    f16x8 v;
#pragma unroll
    for (int j = 0; j < 8; ++j) v[j] = lw[u * 8 + j][row];
    *(f16x8*)(w1img + tbase + (size_t)U * 8) = v;
  }
}

// ---- kernel 2: 256x256x64 fp16 MFMA GEMM, 8-phase schedule ------------------
__global__ __launch_bounds__(THREADS, 2) void k_gemm(
    const float* __restrict__ x, const _Float16* __restrict__ w1img,
    const float* __restrict__ b1, const float* __restrict__ w2,
    float* __restrict__ partial) {
  __shared__ __align__(16) _Float16 Ads[2][BM * BK];   // 2 x 32 KB, swizzled
  __shared__ __align__(16) _Float16 Bds[2][BN * BK];   // 2 x 32 KB, swizzled

  const int t = threadIdx.x;
  const int lane = t & 63;
  const int wid = t >> 6;
  const int wr = wid >> 2, wc = wid & 3;       // 2 x 4 wave grid, wave-tile 128x64
  const int l15 = lane & 15, lhi = lane >> 4;
  const int r7 = l15 & 7;

  const int bid = blockIdx.x;
  const int swz = (bid & 7) * (NWG / 8) + (bid >> 3);
  const int nb = swz & (NBLK - 1);
  const int rb = swz >> 2;
  const int row0 = rb * BM;

  // A staging: thread -> (row = t>>1, aq = t&1 selecting 32-k half), 4 slots
  const int arow = t >> 1;
  const int aq = t & 1;
  const float* xbase = x + (size_t)(row0 + arow) * K_DIM + aq * 32;
  int asl[4];
#pragma unroll
  for (int i = 0; i < 4; ++i) asl[i] = ((aq * 4 + i) ^ (arow & 7)) << 3;

  // B image (pre-swizzled; 4 x 1KB chunks per wave, linear DMA)
  const _Float16* bimg = w1img + ((size_t)(nb * KSTEPS) << 14);
  const int ldsb = wid << 11;

  // fragment read offsets (swizzled)
  const int aoff0 = (wr * 128 + l15) * 64;
  const int boff0 = (wc * 64 + l15) * 64;
  const int su0 = (lhi ^ r7) << 3;
  const int su1 = ((4 + lhi) ^ r7) << 3;

  f32x4 acc[8][4];
#pragma unroll
  for (int m = 0; m < 8; ++m)
#pragma unroll
    for (int n = 0; n < 4; ++n) acc[m][n] = (f32x4){0.f, 0.f, 0.f, 0.f};

  float4 avA[8], avB[8];   // ping-pong A staging banks
  f16x8 bf[8];             // B frags for current K-tile (n*2+su)

  _Float16* Ads0 = &Ads[0][0];
  _Float16* Ads1 = &Ads[1][0];
  _Float16* Bds0 = &Bds[0][0];
  _Float16* Bds1 = &Bds[1][0];

  // 4 phases = one K-tile: compute ACUR/BCUR quad q; write A-slot q of AWDST
  // from AVRD; load AVLD pair q from XK; q>=2: glds from BGS into BGD.
#define HALF_ITER(ACUR, BCUR, AWDST, AVRD, AVLD, XK, BGS, BGD)                 \
  {                                                                            \
    _Pragma("unroll")                                                          \
    for (int q = 0; q < 4; ++q) {                                              \
      if (q == 0) {                                                            \
        VMCNT12();                                                             \
        _Pragma("unroll") for (int n = 0; n < 4; ++n) {                        \
          bf[2 * n]     = *(const f16x8*)((BCUR) + boff0 + n * 1024 + su0);    \
          bf[2 * n + 1] = *(const f16x8*)((BCUR) + boff0 + n * 1024 + su1);    \
        }                                                                      \
      }                                                                        \
      f16x8 af00 = *(const f16x8*)((ACUR) + aoff0 + (2 * q) * 1024 + su0);     \
      f16x8 af01 = *(const f16x8*)((ACUR) + aoff0 + (2 * q) * 1024 + su1);     \
      f16x8 af10 = *(const f16x8*)((ACUR) + aoff0 + (2 * q + 1) * 1024 + su0); \
      f16x8 af11 = *(const f16x8*)((ACUR) + aoff0 + (2 * q + 1) * 1024 + su1); \
      if (q >= 2) {                                                            \
        gld16((BGS) + ldsb + (2 * (q - 2)) * 512 + lane * 8,                   \
              (BGD) + ldsb + (2 * (q - 2)) * 512);                             \
        gld16((BGS) + ldsb + (2 * (q - 2) + 1) * 512 + lane * 8,               \
              (BGD) + ldsb + (2 * (q - 2) + 1) * 512);                         \
      }                                                                        \
      AVLD[2 * q]     = *(const float4*)((XK) + q * 8);                        \
      AVLD[2 * q + 1] = *(const float4*)((XK) + q * 8 + 4);                    \
      SCHEDB();                                                                \
      *(f16x8*)((AWDST) + arow * 64 + asl[q]) =                                \
          cvt8(AVRD[2 * q], AVRD[2 * q + 1]);                                  \
      LGKM0();                                                                 \
      BARR();                                                                  \
      __builtin_amdgcn_s_setprio(1);                                           \
      _Pragma("unroll") for (int n = 0; n < 4; ++n) {                          \
        acc[2 * q][n] = __builtin_amdgcn_mfma_f32_16x16x32_f16(                \
            af00, bf[2 * n], acc[2 * q][n], 0, 0, 0);                          \
        acc[2 * q][n] = __builtin_amdgcn_mfma_f32_16x16x32_f16(                \
            af01, bf[2 * n + 1], acc[2 * q][n], 0, 0, 0);                      \
        acc[2 * q + 1][n] = __builtin_amdgcn_mfma_f32_16x16x32_f16(            \
            af10, bf[2 * n], acc[2 * q + 1][n], 0, 0, 0);                      \
        acc[2 * q + 1][n] = __builtin_amdgcn_mfma_f32_16x16x32_f16(            \
            af11, bf[2 * n + 1], acc[2 * q + 1][n], 0, 0, 0);                  \
      }                                                                        \
      __builtin_amdgcn_s_setprio(0);                                           \
      BARR();                                                                  \
    }                                                                          \
  }

  // ---- prologue: A(0)->Ads0, avB <- A(1), B(0)->Bds0, B(1)->Bds1 ----
  {
    const float* xp = xbase;
#pragma unroll
    for (int j = 0; j < 8; ++j) avA[j] = *(const float4*)(xp + j * 4);
  }
  SCHEDB();
#pragma unroll
  for (int g = 0; g < 4; ++g)
    gld16(bimg + ldsb + g * 512 + lane * 8, Bds0 + ldsb + g * 512);
  {
    const _Float16* b1s = bimg + ((size_t)1 << 14);
#pragma unroll
    for (int g = 0; g < 4; ++g)
      gld16(b1s + ldsb + g * 512 + lane * 8, Bds1 + ldsb + g * 512);
  }
  SCHEDB();
#pragma unroll
  for (int i = 0; i < 4; ++i)   // compiler waits avA (leaves B glds in flight)
    *(f16x8*)(Ads0 + arow * 64 + asl[i]) = cvt8(avA[2 * i], avA[2 * i + 1]);
  {
    const float* xp = xbase + BK;
#pragma unroll
    for (int j = 0; j < 8; ++j) avB[j] = *(const float4*)(xp + j * 4);
  }
  VMCNT12();    // outstanding: B0(4)+B1(4)+avB(8)=16 -> drains B(0)
  LGKM0();
  BARR();

  // ---- main loop: iter processes (kt, kt+1); stages (kt+2, kt+3) ----
  for (int it = 0; it < KSTEPS / 2; ++it) {
    const int kt = 2 * it;
    const int c2 = (kt + 2 < KSTEPS) ? kt + 2 : KSTEPS - 1;
    const int c3 = (kt + 3 < KSTEPS) ? kt + 3 : KSTEPS - 1;
    const float* xk2 = xbase + c2 * BK;
    const float* xk3 = xbase + c3 * BK;
    const _Float16* bs2 = bimg + ((size_t)c2 << 14);
    const _Float16* bs3 = bimg + ((size_t)c3 << 14);
    // ph 0-3: compute kt (buf0); write A(kt+1)->Ads1 from avB; load avA<-A(kt+2);
    //         glds B(kt+2)->Bds0
    HALF_ITER(Ads0, Bds0, Ads1, avB, avA, xk2, bs2, Bds0);
    // ph 4-7: compute kt+1 (buf1); write A(kt+2)->Ads0 from avA; load avB<-A(kt+3);
    //         glds B(kt+3)->Bds1
    HALF_ITER(Ads1, Bds1, Ads0, avA, avB, xk3, bs3, Bds1);
  }
#undef HALF_ITER

  // ---- fused epilogue: gelu -> *W2 -> per-row partial logits ----
  float* pl = (float*)Ads0;   // [256][4][3] overlay (12 KB < 32 KB)
  float w2v[4][3], b1v[4];
  const int n0g = nb * BN;
#pragma unroll
  for (int n = 0; n < 4; ++n) {
    const int gc = n0g + wc * 64 + n * 16 + l15;
    b1v[n] = b1[gc];
    w2v[n][0] = w2[gc * 3 + 0];
    w2v[n][1] = w2[gc * 3 + 1];
    w2v[n][2] = w2[gc * 3 + 2];
  }
#pragma unroll
  for (int m = 0; m < 8; ++m) {
#pragma unroll
    for (int j = 0; j < 4; ++j) {
      float s0 = 0.f, s1 = 0.f, s2 = 0.f;
#pragma unroll
      for (int n = 0; n < 4; ++n) {
        const float g = gelu_exact(acc[m][n][j] + b1v[n]);
        s0 += g * w2v[n][0];
        s1 += g * w2v[n][1];
        s2 += g * w2v[n][2];
      }
#pragma unroll
      for (int off = 1; off < 16; off <<= 1) {
        s0 += __shfl_xor(s0, off, 64);
        s1 += __shfl_xor(s1, off, 64);
        s2 += __shfl_xor(s2, off, 64);
      }
      if (l15 == 0) {
        const int r = wr * 128 + m * 16 + lhi * 4 + j;
        pl[r * 12 + wc * 3 + 0] = s0;
        pl[r * 12 + wc * 3 + 1] = s1;
        pl[r * 12 + wc * 3 + 2] = s2;
      }
    }
  }
  LGKM0();
  BARR();
  if (t < BM) {
#pragma unroll
    for (int e = 0; e < 3; ++e) {
      partial[(size_t)(row0 + t) * 12 + nb * 3 + e] =
          pl[t * 12 + e] + pl[t * 12 + 3 + e] + pl[t * 12 + 6 + e] + pl[t * 12 + 9 + e];
    }
  }
}

// ---- shared finalize: softmax + top-k mask + renorm -------------------------
__device__ __forceinline__ void gate_store(float* __restrict__ out, int r,
                                           float l0, float l1, float l2, int kk) {
  const float mx = fmaxf(l0, fmaxf(l1, l2));
  const float e0 = expf(l0 - mx), e1 = expf(l1 - mx), e2 = expf(l2 - mx);
  const float s = e0 + e1 + e2;
  const float g0 = e0 / s, g1 = e1 / s, g2 = e2 / s;
  const int r0 = (g1 > g0) + (g2 > g0);
  const int r1 = (g0 >= g1) + (g2 > g1);
  const int r2 = (g0 >= g2) + (g1 >= g2);
  const float m0 = (r0 < kk) ? 1.f : 0.f;
  const float m1 = (r1 < kk) ? 1.f : 0.f;
  const float m2 = (r2 < kk) ? 1.f : 0.f;
  const float ks = g0 * m0 + g1 * m1 + g2 * m2;
  const float inv = 1.f / (ks + 1e-8f);
  float* go = out + (size_t)r * 3;
  go[0] = g0 * m0 * inv;
  go[1] = g1 * m1 * inv;
  go[2] = g2 * m2 * inv;
  float* mo = out + (size_t)B_ROWS * 3 + (size_t)r * 3;
  mo[0] = m0;
  mo[1] = m1;
  mo[2] = m2;
}

// ---- kernel 3: logits -> outputs + fallback detect --------------------------
__global__ void k_gate(const float* __restrict__ partial, const float* __restrict__ b2,
                       const int* __restrict__ kp, float* __restrict__ out,
                       int* __restrict__ fb_cnt, int* __restrict__ fb_rows) {
  const int r = blockIdx.x * blockDim.x + threadIdx.x;
  if (r >= B_ROWS) return;
  const float* p = partial + (size_t)r * 12;
  float l0 = b2[0], l1 = b2[1], l2 = b2[2];
#pragma unroll
  for (int c = 0; c < 4; ++c) {
    l0 += p[c * 3 + 0];
    l1 += p[c * 3 + 1];
    l2 += p[c * 3 + 2];
  }
  int kk = *kp;
  kk = kk < 3 ? kk : 3;
  gate_store(out, r, l0, l1, l2, kk);
  const float mx = fmaxf(l0, fmaxf(l1, l2));
  const float mn = fminf(l0, fminf(l1, l2));
  const float mid = l0 + l1 + l2 - mx - mn;
  float gap = 1e30f;
  if (kk == 1) gap = mx - mid;
  else if (kk == 2) gap = mid - mn;
  if (gap < MARGIN) {
    const int i = atomicAdd(fb_cnt, 1);
    if (i < FB_CAP) fb_rows[i] = r;
  }
}

// ---- kernel 4: fp32 exact recompute of near-tie rows (32-row slots) ---------
__global__ __launch_bounds__(256) void k_fb_gemm(
    const float* __restrict__ x, const float* __restrict__ w1,
    const float* __restrict__ b1, const float* __restrict__ w2,
    const int* __restrict__ fb_cnt, const int* __restrict__ fb_rows,
    float* __restrict__ fb_partial) {
  int count = *fb_cnt;
  count = count < FB_CAP ? count : FB_CAP;
  if (count == 0) return;
  const int nc = blockIdx.y, n0 = nc * 64;
  const int t = threadIdx.x, col = t & 63, wrow = t >> 6;
  __shared__ float Xs[32][64];
  __shared__ float Ws[64][64];
  for (int slot = blockIdx.x; slot * 32 < count; slot += gridDim.x) {
    float accr[8] = {0.f, 0.f, 0.f, 0.f, 0.f, 0.f, 0.f, 0.f};
    for (int kt = 0; kt < K_DIM / 64; ++kt) {
      const int k0 = kt * 64;
      __syncthreads();
#pragma unroll
      for (int i = 0; i < 2; ++i) {
        const int idx = i * 256 + t, rr = idx >> 4, c4 = (idx & 15) << 2;
        int gi = slot * 32 + rr;
        gi = gi < count ? gi : count - 1;
        *(float4*)&Xs[rr][c4] = *(const float4*)(x + (size_t)fb_rows[gi] * K_DIM + k0 + c4);
      }
#pragma unroll
      for (int i = 0; i < 4; ++i) {
        const int idx = i * 256 + t, rr = idx >> 4, c4 = (idx & 15) << 2;
        *(float4*)&Ws[rr][c4] = *(const float4*)(w1 + (size_t)(k0 + rr) * N_DIM + n0 + c4);
      }
      __syncthreads();
#pragma unroll 4
      for (int kk = 0; kk < 64; ++kk) {
        const float wv = Ws[kk][col];
#pragma unroll
        for (int rr = 0; rr < 8; ++rr) accr[rr] += Xs[wrow * 8 + rr][kk] * wv;
      }
    }
    const float bv = b1[n0 + col];
    const float w20 = w2[(n0 + col) * 3 + 0];
    const float w21 = w2[(n0 + col) * 3 + 1];
    const float w22 = w2[(n0 + col) * 3 + 2];
#pragma unroll
    for (int rr = 0; rr < 8; ++rr) {
      const float g = gelu_exact(accr[rr] + bv);
      float c0 = g * w20, c1 = g * w21, c2 = g * w22;
#pragma unroll
      for (int off = 1; off < 64; off <<= 1) {
        c0 += __shfl_xor(c0, off, 64);
        c1 += __shfl_xor(c1, off, 64);
        c2 += __shfl_xor(c2, off, 64);
      }
      const int gi = slot * 32 + wrow * 8 + rr;
      if (col == 0 && gi < count) {
        float* fp = fb_partial + ((size_t)gi * 16 + nc) * 3;
        fp[0] = c0;
        fp[1] = c1;
        fp[2] = c2;
      }
    }
  }
}

// ---- kernel 5: finalize fallback rows ---------------------------------------
__global__ void k_fb_fin(const float* __restrict__ fb_partial, const float* __restrict__ b2,
                         const int* __restrict__ kp, const int* __restrict__ fb_cnt,
                         const int* __restrict__ fb_rows, float* __restrict__ out) {
  const int i = blockIdx.x * blockDim.x + threadIdx.x;
  int count = *fb_cnt;
  count = count < FB_CAP ? count : FB_CAP;
  if (i >= count) return;
  const int r = fb_rows[i];
  float l0 = b2[0], l1 = b2[1], l2 = b2[2];
  const float* fp = fb_partial + (size_t)i * 48;
#pragma unroll
  for (int c = 0; c < 16; ++c) {
    l0 += fp[c * 3 + 0];
    l1 += fp[c * 3 + 1];
    l2 += fp[c * 3 + 2];
  }
  int kk = *kp;
  kk = kk < 3 ? kk : 3;
  gate_store(out, r, l0, l1, l2, kk);
}

extern "C" void kernel_launch(void* const* d_in, const int* in_sizes, int n_in,
                              void* d_out, int out_size, void* d_ws, size_t ws_size,
                              hipStream_t stream) {
  (void)in_sizes; (void)n_in; (void)out_size; (void)ws_size;
  const float* x  = (const float*)d_in[0];
  const float* w1 = (const float*)d_in[1];
  const float* b1 = (const float*)d_in[2];
  const float* w2 = (const float*)d_in[3];
  const float* b2 = (const float*)d_in[4];
  const int*   kp = (const int*)d_in[5];
  float* out = (float*)d_out;

  uint8_t* ws = (uint8_t*)d_ws;
  _Float16* w1img   = (_Float16*)(ws);            // 6,291,456 B
  float* partial    = (float*)(ws + 6291456);     // 3,145,728 B
  int* fb_cnt       = (int*)(ws + 9437184);       // 256 B
  int* fb_rows      = (int*)(ws + 9437440);       // 32,768 B
  float* fb_partial = (float*)(ws + 9470208);     // 1,572,864 B (~11 MB total)

  k_w1t<<<dim3(KSTEPS, NBLK), 256, 0, stream>>>(w1, w1img, fb_cnt);
  k_gemm<<<dim3(NWG), THREADS, 0, stream>>>(x, w1img, b1, w2, partial);
  k_gate<<<dim3(B_ROWS / 256), 256, 0, stream>>>(partial, b2, kp, out, fb_cnt, fb_rows);
  k_fb_gemm<<<dim3(16, 16), 256, 0, stream>>>(x, w1, b1, w2, fb_cnt, fb_rows, fb_partial);
  k_fb_fin<<<dim3(FB_CAP / 256), 256, 0, stream>>>(fb_partial, b2, kp, fb_cnt, fb_rows, out);
}

// Round 9
// 1095.456 us; speedup vs baseline: 1.1234x; 1.1234x over previous
//
#include <hip/hip_runtime.h>
#include <hip/hip_fp16.h>
#include <stdint.h>

#define B_ROWS 65536
#define K_DIM 3072
#define N_DIM 1024

#define BM 256
#define BN 256
#define BK 64
#define NBLK 4            // N_DIM / BN
#define THREADS 512
#define KSTEPS (K_DIM / BK)   // 48
#define MARGIN 6.0e-3f
#define FB_CAP 8192
#define NWG ((B_ROWS / BM) * NBLK)   // 1024

typedef _Float16 f16x8 __attribute__((ext_vector_type(8)));
typedef float f32x4 __attribute__((ext_vector_type(4)));

#define BARR() __builtin_amdgcn_s_barrier()
#define VMCNT0() asm volatile("s_waitcnt vmcnt(0)" ::: "memory")
#define LGKM0() asm volatile("s_waitcnt lgkmcnt(0)" ::: "memory")
#define SCHEDB() __builtin_amdgcn_sched_barrier(0)

__device__ __forceinline__ float gelu_exact(float v) {
  return 0.5f * v * (1.0f + erff(v * 0.7071067811865476f));
}

__device__ __forceinline__ void gld16(const void* g, void* l) {
  __builtin_amdgcn_global_load_lds(
      (const __attribute__((address_space(1))) void*)g,
      (__attribute__((address_space(3))) void*)l, 16, 0, 0);
}

__device__ __forceinline__ f16x8 cvt8(const float4 a, const float4 b) {
  f16x8 h;
  h[0] = (_Float16)a.x; h[1] = (_Float16)a.y; h[2] = (_Float16)a.z; h[3] = (_Float16)a.w;
  h[4] = (_Float16)b.x; h[5] = (_Float16)b.y; h[6] = (_Float16)b.z; h[7] = (_Float16)b.w;
  return h;
}

// ---- kernel 1: build swizzled fp16 B-image of w1 (+ zero fb_cnt) ------------
// Image per (nb, kt): 256 rows (n) x 64 cols (k) fp16, 32KB, laid out exactly
// as the LDS tile: element (row, su*8+j) = w1[kt*64 + (su^(row&7))*8 + j][nb*256+row]
__global__ void k_w1t(const float* __restrict__ w1, _Float16* __restrict__ w1img,
                      int* __restrict__ fb_cnt) {
  if (blockIdx.x == 0 && blockIdx.y == 0 && threadIdx.x == 0) *fb_cnt = 0;
  __shared__ _Float16 lw[64][264];
  const int kt = blockIdx.x, nb = blockIdx.y;
  const int t = threadIdx.x;
  for (int r = 0; r < 64; ++r)
    lw[r][t] = (_Float16)w1[(size_t)(kt * 64 + r) * N_DIM + nb * 256 + t];
  __syncthreads();
  const size_t tbase = ((size_t)(nb * KSTEPS + kt)) << 14;
#pragma unroll
  for (int i = 0; i < 8; ++i) {
    const int U = i * 256 + t;
    const int row = U >> 3, su = U & 7;
    const int u = su ^ (row & 7);
    f16x8 v;
#pragma unroll
    for (int j = 0; j < 8; ++j) v[j] = lw[u * 8 + j][row];
    *(f16x8*)(w1img + tbase + (size_t)U * 8) = v;
  }
}

// ---- kernel 2: 256x256x64 fp16 MFMA GEMM, template-exact 8-phase ------------
__global__ __launch_bounds__(THREADS, 2) void k_gemm(
    const float* __restrict__ x, const _Float16* __restrict__ w1img,
    const float* __restrict__ b1, const float* __restrict__ w2,
    float* __restrict__ partial) {
  __shared__ __align__(16) _Float16 Ads[2][BM * BK];   // 2 x 32 KB, swizzled
  __shared__ __align__(16) _Float16 Bds[2][BN * BK];   // 2 x 32 KB, swizzled

  const int t = threadIdx.x;
  const int lane = t & 63;
  const int wid = t >> 6;
  const int wr = wid >> 2, wc = wid & 3;       // 2 x 4 waves, wave-tile 128x64
  const int l15 = lane & 15, lhi = lane >> 4;
  const int r7 = l15 & 7;

  const int bid = blockIdx.x;
  const int swz = (bid & 7) * (NWG / 8) + (bid >> 3);
  const int nb = swz & (NBLK - 1);
  const int rb = swz >> 2;
  const int row0 = rb * BM;

  // A staging: thread -> (row = t>>1, aq = t&1 selecting 32-k half)
  const int arow = t >> 1;
  const int aq = t & 1;
  const float* xbase = x + (size_t)(row0 + arow) * K_DIM + aq * 32;
  int asl[4];
#pragma unroll
  for (int i = 0; i < 4; ++i) asl[i] = ((aq * 4 + i) ^ (arow & 7)) << 3;

  // B image (pre-swizzled; 4 x 1KB chunks per wave, linear DMA)
  const _Float16* bimg = w1img + ((size_t)(nb * KSTEPS) << 14);
  const int ldsb = wid << 11;

  // fragment read offsets (swizzled)
  const int aoff0 = (wr * 128 + l15) * 64;
  const int boff0 = (wc * 64 + l15) * 64;
  const int su0 = (lhi ^ r7) << 3;
  const int su1 = ((4 + lhi) ^ r7) << 3;

  f32x4 acc[8][4];
#pragma unroll
  for (int m = 0; m < 8; ++m)
#pragma unroll
    for (int n = 0; n < 4; ++n) acc[m][n] = (f32x4){0.f, 0.f, 0.f, 0.f};

  float4 av[8];    // single A staging bank (load q0/q1 -> write q2/q3)
  f16x8 bf[8];     // B frags for current K-tile (held across the 4 phases)

  _Float16* Acur = &Ads[0][0];
  _Float16* Anxt = &Ads[1][0];
  _Float16* Bcur = &Bds[0][0];
  _Float16* Bnxt = &Bds[1][0];

  // One phase: ds-reads BEFORE barrier (latency hides under rendezvous),
  // stage-issues, BARR, LGKM0 (after barrier - template order), MFMA, BARR.
#define PHASE(Q, STAGE)                                                        \
  {                                                                            \
    if ((Q) == 0) {                                                            \
      _Pragma("unroll") for (int n = 0; n < 4; ++n) {                          \
        bf[2 * n]     = *(const f16x8*)(Bcur + boff0 + n * 1024 + su0);        \
        bf[2 * n + 1] = *(const f16x8*)(Bcur + boff0 + n * 1024 + su1);        \
      }                                                                        \
    }                                                                          \
    f16x8 af00 = *(const f16x8*)(Acur + aoff0 + (2 * (Q)) * 1024 + su0);       \
    f16x8 af01 = *(const f16x8*)(Acur + aoff0 + (2 * (Q)) * 1024 + su1);       \
    f16x8 af10 = *(const f16x8*)(Acur + aoff0 + (2 * (Q) + 1) * 1024 + su0);   \
    f16x8 af11 = *(const f16x8*)(Acur + aoff0 + (2 * (Q) + 1) * 1024 + su1);   \
    STAGE;                                                                     \
    BARR();                                                                    \
    LGKM0();                                                                   \
    __builtin_amdgcn_s_setprio(1);                                             \
    _Pragma("unroll") for (int n = 0; n < 4; ++n) {                            \
      acc[2 * (Q)][n] = __builtin_amdgcn_mfma_f32_16x16x32_f16(                \
          af00, bf[2 * n], acc[2 * (Q)][n], 0, 0, 0);                          \
      acc[2 * (Q)][n] = __builtin_amdgcn_mfma_f32_16x16x32_f16(                \
          af01, bf[2 * n + 1], acc[2 * (Q)][n], 0, 0, 0);                      \
      acc[2 * (Q) + 1][n] = __builtin_amdgcn_mfma_f32_16x16x32_f16(            \
          af10, bf[2 * n], acc[2 * (Q) + 1][n], 0, 0, 0);                      \
      acc[2 * (Q) + 1][n] = __builtin_amdgcn_mfma_f32_16x16x32_f16(            \
          af11, bf[2 * n + 1], acc[2 * (Q) + 1][n], 0, 0, 0);                  \
    }                                                                          \
    __builtin_amdgcn_s_setprio(0);                                             \
    BARR();                                                                    \
  }

  // ---- prologue: stage tile 0 (A regs -> Ads0, B glds -> Bds0) ----
  {
#pragma unroll
    for (int j = 0; j < 8; ++j) av[j] = *(const float4*)(xbase + j * 4);
    SCHEDB();
#pragma unroll
    for (int g = 0; g < 4; ++g)
      gld16(bimg + ldsb + g * 512 + lane * 8, Bcur + ldsb + g * 512);
    SCHEDB();
#pragma unroll
    for (int i = 0; i < 4; ++i)   // auto-vmcnt drains av, leaves B glds
      *(f16x8*)(Acur + arow * 64 + asl[i]) = cvt8(av[2 * i], av[2 * i + 1]);
    VMCNT0();
    LGKM0();
    BARR();
  }

  // ---- main loop: tile kt computed; tile kt+1 staged within the 4 phases ----
  // FIFO invariant: q3's A-write auto-vmcnt (av[7]) drains B(kt+1) glds
  // (issued q0/q1, 2-3 phases old, L2-hot) -> next tile's bf reads are safe
  // after q3's trailing barrier. No explicit vmcnt in the loop.
  for (int kt = 0; kt < KSTEPS - 1; ++kt) {
    const float* xn = xbase + (kt + 1) * BK;
    const _Float16* bn = bimg + ((size_t)(kt + 1) << 14);
    PHASE(0, {
      gld16(bn + ldsb + lane * 8, Bnxt + ldsb);
      gld16(bn + ldsb + 512 + lane * 8, Bnxt + ldsb + 512);
      av[0] = *(const float4*)(xn);
      av[1] = *(const float4*)(xn + 4);
      av[2] = *(const float4*)(xn + 8);
      av[3] = *(const float4*)(xn + 12);
    });
    PHASE(1, {
      gld16(bn + ldsb + 1024 + lane * 8, Bnxt + ldsb + 1024);
      gld16(bn + ldsb + 1536 + lane * 8, Bnxt + ldsb + 1536);
      av[4] = *(const float4*)(xn + 16);
      av[5] = *(const float4*)(xn + 20);
      av[6] = *(const float4*)(xn + 24);
      av[7] = *(const float4*)(xn + 28);
    });
    PHASE(2, {
      *(f16x8*)(Anxt + arow * 64 + asl[0]) = cvt8(av[0], av[1]);
      *(f16x8*)(Anxt + arow * 64 + asl[1]) = cvt8(av[2], av[3]);
    });
    PHASE(3, {
      *(f16x8*)(Anxt + arow * 64 + asl[2]) = cvt8(av[4], av[5]);
      *(f16x8*)(Anxt + arow * 64 + asl[3]) = cvt8(av[6], av[7]);
    });
    { _Float16* tp = Acur; Acur = Anxt; Anxt = tp;
      tp = Bcur; Bcur = Bnxt; Bnxt = tp; }
  }
  // ---- tail tile 47: compute only ----
  PHASE(0, {});
  PHASE(1, {});
  PHASE(2, {});
  PHASE(3, {});
#undef PHASE

  // ---- fused epilogue: gelu -> *W2 -> per-row partial logits ----
  float* pl = (float*)&Ads[0][0];   // [256][4][3] overlay (12 KB < 32 KB)
  float w2v[4][3], b1v[4];
  const int n0g = nb * BN;
#pragma unroll
  for (int n = 0; n < 4; ++n) {
    const int gc = n0g + wc * 64 + n * 16 + l15;
    b1v[n] = b1[gc];
    w2v[n][0] = w2[gc * 3 + 0];
    w2v[n][1] = w2[gc * 3 + 1];
    w2v[n][2] = w2[gc * 3 + 2];
  }
#pragma unroll
  for (int m = 0; m < 8; ++m) {
#pragma unroll
    for (int j = 0; j < 4; ++j) {
      float s0 = 0.f, s1 = 0.f, s2 = 0.f;
#pragma unroll
      for (int n = 0; n < 4; ++n) {
        const float g = gelu_exact(acc[m][n][j] + b1v[n]);
        s0 += g * w2v[n][0];
        s1 += g * w2v[n][1];
        s2 += g * w2v[n][2];
      }
#pragma unroll
      for (int off = 1; off < 16; off <<= 1) {
        s0 += __shfl_xor(s0, off, 64);
        s1 += __shfl_xor(s1, off, 64);
        s2 += __shfl_xor(s2, off, 64);
      }
      if (l15 == 0) {
        const int r = wr * 128 + m * 16 + lhi * 4 + j;
        pl[r * 12 + wc * 3 + 0] = s0;
        pl[r * 12 + wc * 3 + 1] = s1;
        pl[r * 12 + wc * 3 + 2] = s2;
      }
    }
  }
  LGKM0();
  BARR();
  if (t < BM) {
#pragma unroll
    for (int e = 0; e < 3; ++e) {
      partial[(size_t)(row0 + t) * 12 + nb * 3 + e] =
          pl[t * 12 + e] + pl[t * 12 + 3 + e] + pl[t * 12 + 6 + e] + pl[t * 12 + 9 + e];
    }
  }
}

// ---- shared finalize: softmax + top-k mask + renorm -------------------------
__device__ __forceinline__ void gate_store(float* __restrict__ out, int r,
                                           float l0, float l1, float l2, int kk) {
  const float mx = fmaxf(l0, fmaxf(l1, l2));
  const float e0 = expf(l0 - mx), e1 = expf(l1 - mx), e2 = expf(l2 - mx);
  const float s = e0 + e1 + e2;
  const float g0 = e0 / s, g1 = e1 / s, g2 = e2 / s;
  const int r0 = (g1 > g0) + (g2 > g0);
  const int r1 = (g0 >= g1) + (g2 > g1);
  const int r2 = (g0 >= g2) + (g1 >= g2);
  const float m0 = (r0 < kk) ? 1.f : 0.f;
  const float m1 = (r1 < kk) ? 1.f : 0.f;
  const float m2 = (r2 < kk) ? 1.f : 0.f;
  const float ks = g0 * m0 + g1 * m1 + g2 * m2;
  const float inv = 1.f / (ks + 1e-8f);
  float* go = out + (size_t)r * 3;
  go[0] = g0 * m0 * inv;
  go[1] = g1 * m1 * inv;
  go[2] = g2 * m2 * inv;
  float* mo = out + (size_t)B_ROWS * 3 + (size_t)r * 3;
  mo[0] = m0;
  mo[1] = m1;
  mo[2] = m2;
}

// ---- kernel 3: logits -> outputs + fallback detect --------------------------
__global__ void k_gate(const float* __restrict__ partial, const float* __restrict__ b2,
                       const int* __restrict__ kp, float* __restrict__ out,
                       int* __restrict__ fb_cnt, int* __restrict__ fb_rows) {
  const int r = blockIdx.x * blockDim.x + threadIdx.x;
  if (r >= B_ROWS) return;
  const float* p = partial + (size_t)r * 12;
  float l0 = b2[0], l1 = b2[1], l2 = b2[2];
#pragma unroll
  for (int c = 0; c < 4; ++c) {
    l0 += p[c * 3 + 0];
    l1 += p[c * 3 + 1];
    l2 += p[c * 3 + 2];
  }
  int kk = *kp;
  kk = kk < 3 ? kk : 3;
  gate_store(out, r, l0, l1, l2, kk);
  const float mx = fmaxf(l0, fmaxf(l1, l2));
  const float mn = fminf(l0, fminf(l1, l2));
  const float mid = l0 + l1 + l2 - mx - mn;
  float gap = 1e30f;
  if (kk == 1) gap = mx - mid;
  else if (kk == 2) gap = mid - mn;
  if (gap < MARGIN) {
    const int i = atomicAdd(fb_cnt, 1);
    if (i < FB_CAP) fb_rows[i] = r;
  }
}

// ---- kernel 4: fp32 exact recompute of near-tie rows (32-row slots) ---------
__global__ __launch_bounds__(256) void k_fb_gemm(
    const float* __restrict__ x, const float* __restrict__ w1,
    const float* __restrict__ b1, const float* __restrict__ w2,
    const int* __restrict__ fb_cnt, const int* __restrict__ fb_rows,
    float* __restrict__ fb_partial) {
  int count = *fb_cnt;
  count = count < FB_CAP ? count : FB_CAP;
  if (count == 0) return;
  const int nc = blockIdx.y, n0 = nc * 64;
  const int t = threadIdx.x, col = t & 63, wrow = t >> 6;
  __shared__ float Xs[32][64];
  __shared__ float Ws[64][64];
  for (int slot = blockIdx.x; slot * 32 < count; slot += gridDim.x) {
    float accr[8] = {0.f, 0.f, 0.f, 0.f, 0.f, 0.f, 0.f, 0.f};
    for (int kt = 0; kt < K_DIM / 64; ++kt) {
      const int k0 = kt * 64;
      __syncthreads();
#pragma unroll
      for (int i = 0; i < 2; ++i) {
        const int idx = i * 256 + t, rr = idx >> 4, c4 = (idx & 15) << 2;
        int gi = slot * 32 + rr;
        gi = gi < count ? gi : count - 1;
        *(float4*)&Xs[rr][c4] = *(const float4*)(x + (size_t)fb_rows[gi] * K_DIM + k0 + c4);
      }
#pragma unroll
      for (int i = 0; i < 4; ++i) {
        const int idx = i * 256 + t, rr = idx >> 4, c4 = (idx & 15) << 2;
        *(float4*)&Ws[rr][c4] = *(const float4*)(w1 + (size_t)(k0 + rr) * N_DIM + n0 + c4);
      }
      __syncthreads();
#pragma unroll 4
      for (int kk = 0; kk < 64; ++kk) {
        const float wv = Ws[kk][col];
#pragma unroll
        for (int rr = 0; rr < 8; ++rr) accr[rr] += Xs[wrow * 8 + rr][kk] * wv;
      }
    }
    const float bv = b1[n0 + col];
    const float w20 = w2[(n0 + col) * 3 + 0];
    const float w21 = w2[(n0 + col) * 3 + 1];
    const float w22 = w2[(n0 + col) * 3 + 2];
#pragma unroll
    for (int rr = 0; rr < 8; ++rr) {
      const float g = gelu_exact(accr[rr] + bv);
      float c0 = g * w20, c1 = g * w21, c2 = g * w22;
#pragma unroll
      for (int off = 1; off < 64; off <<= 1) {
        c0 += __shfl_xor(c0, off, 64);
        c1 += __shfl_xor(c1, off, 64);
        c2 += __shfl_xor(c2, off, 64);
      }
      const int gi = slot * 32 + wrow * 8 + rr;
      if (col == 0 && gi < count) {
        float* fp = fb_partial + ((size_t)gi * 16 + nc) * 3;
        fp[0] = c0;
        fp[1] = c1;
        fp[2] = c2;
      }
    }
  }
}

// ---- kernel 5: finalize fallback rows ---------------------------------------
__global__ void k_fb_fin(const float* __restrict__ fb_partial, const float* __restrict__ b2,
                         const int* __restrict__ kp, const int* __restrict__ fb_cnt,
                         const int* __restrict__ fb_rows, float* __restrict__ out) {
  const int i = blockIdx.x * blockDim.x + threadIdx.x;
  int count = *fb_cnt;
  count = count < FB_CAP ? count : FB_CAP;
  if (i >= count) return;
  const int r = fb_rows[i];
  float l0 = b2[0], l1 = b2[1], l2 = b2[2];
  const float* fp = fb_partial + (size_t)i * 48;
#pragma unroll
  for (int c = 0; c < 16; ++c) {
    l0 += fp[c * 3 + 0];
    l1 += fp[c * 3 + 1];
    l2 += fp[c * 3 + 2];
  }
  int kk = *kp;
  kk = kk < 3 ? kk : 3;
  gate_store(out, r, l0, l1, l2, kk);
}

extern "C" void kernel_launch(void* const* d_in, const int* in_sizes, int n_in,
                              void* d_out, int out_size, void* d_ws, size_t ws_size,
                              hipStream_t stream) {
  (void)in_sizes; (void)n_in; (void)out_size; (void)ws_size;
  const float* x  = (const float*)d_in[0];
  const float* w1 = (const float*)d_in[1];
  const float* b1 = (const float*)d_in[2];
  const float* w2 = (const float*)d_in[3];
  const float* b2 = (const float*)d_in[4];
  const int*   kp = (const int*)d_in[5];
  float* out = (float*)d_out;

  uint8_t* ws = (uint8_t*)d_ws;
  _Float16* w1img   = (_Float16*)(ws);            // 6,291,456 B
  float* partial    = (float*)(ws + 6291456);     // 3,145,728 B
  int* fb_cnt       = (int*)(ws + 9437184);       // 256 B
  int* fb_rows      = (int*)(ws + 9437440);       // 32,768 B
  float* fb_partial = (float*)(ws + 9470208);     // 1,572,864 B (~11 MB total)

  k_w1t<<<dim3(KSTEPS, NBLK), 256, 0, stream>>>(w1, w1img, fb_cnt);
  k_gemm<<<dim3(NWG), THREADS, 0, stream>>>(x, w1img, b1, w2, partial);
  k_gate<<<dim3(B_ROWS / 256), 256, 0, stream>>>(partial, b2, kp, out, fb_cnt, fb_rows);
  k_fb_gemm<<<dim3(16, 16), 256, 0, stream>>>(x, w1, b1, w2, fb_cnt, fb_rows, fb_partial);
  k_fb_fin<<<dim3(FB_CAP / 256), 256, 0, stream>>>(fb_partial, b2, kp, fb_cnt, fb_rows, out);
}